// Round 11
// baseline (691.580 us; speedup 1.0000x reference)
//
#include <hip/hip_runtime.h>
#include <hip/hip_bf16.h>

#define BATCH 16
#define CH    256
#define HH    96
#define WW    96
#define HWSZ  9216     // 96*96
#define FCH   256
#define PP    256      // 16*16 pooled positions

typedef float f32x4 __attribute__((ext_vector_type(4)));
typedef short bf16x8 __attribute__((ext_vector_type(8)));
typedef unsigned short ushortT;

#define APAD_ELEMS 2458624   // 98*32*98*8 ushorts per batch
#define APAD_CHUNKS 307328   // uint4 chunks per batch

__device__ __forceinline__ void gload16(const void* g, void* l) {
    __builtin_amdgcn_global_load_lds((const __attribute__((address_space(1))) void*)g,
                                     (__attribute__((address_space(3))) void*)l, 16, 0, 0);
}
__device__ __forceinline__ float bfu2f(ushortT u) {
    return __uint_as_float(((unsigned)u) << 16);
}
__device__ __forceinline__ ushortT f2bfu(float f) {
    __hip_bfloat16 hb = __float2bfloat16(f);
    return *reinterpret_cast<ushortT*>(&hb);
}

// ---------------------------------------------------------------------------
// fused: pack feat -> bf16 chunked [b][cb=32][hw][8ci]  +  rnorm[b,hw]
__global__ void fpack_k(const float* __restrict__ feat, ushortT* __restrict__ fpack,
                        float* __restrict__ rnorm)
{
    int b = blockIdx.y;
    int hw = blockIdx.x * 256 + threadIdx.x;
    const float* src = feat + (size_t)b * CH * HWSZ + hw;
    uint4* dst = (uint4*)fpack + (size_t)b * 32 * HWSZ + hw;
    float ss = 0.f;
    for (int cb = 0; cb < 32; ++cb) {
        union { ushortT u[8]; uint4 v; } pk;
#pragma unroll
        for (int i = 0; i < 8; ++i) {
            float v = src[(size_t)(cb * 8 + i) * HWSZ];
            ss += v * v;
            pk.u[i] = f2bfu(v);
        }
        dst[(size_t)cb * HWSZ] = pk.v;
    }
    rnorm[b * HWSZ + hw] = 1.0f / fmaxf(sqrtf(ss), 1e-12f);
}

// ---------------------------------------------------------------------------
// 6x6 average pool from fpack (bf16, L3-resident): grid (32 cb, B), 256 thr
__global__ void pool16b_k(const ushortT* __restrict__ fpack, float* __restrict__ pooled)
{
    int cb = blockIdx.x, b = blockIdx.y;
    const uint4* fp = (const uint4*)fpack + ((size_t)b * 32 + cb) * HWSZ;
    int t = threadIdx.x;
    int pr = t >> 4, pc = t & 15;
    float s[8] = {};
#pragma unroll
    for (int i = 0; i < 6; ++i) {
#pragma unroll
        for (int j = 0; j < 6; ++j) {
            uint4 v = fp[(pr * 6 + i) * WW + pc * 6 + j];
            const ushortT* u = (const ushortT*)&v;
#pragma unroll
            for (int k = 0; k < 8; ++k) s[k] += bfu2f(u[k]);
        }
    }
#pragma unroll
    for (int k = 0; k < 8; ++k)
        pooled[((size_t)b * CH + cb * 8 + k) * PP + t] = s[k] * (1.0f / 36.0f);
}

// ---------------------------------------------------------------------------
// M[b,o,c] = sum_p W1[o,p] * pooled[b,c,p]  (f32 acc) -> bf16 packed
__global__ void gemmM_k(const float* __restrict__ W1, const float* __restrict__ pooled,
                        ushortT* __restrict__ Mb16)
{
    int b = blockIdx.z;
    int o0 = blockIdx.y * 16, c0 = blockIdx.x * 16;
    int ty = threadIdx.y, tx = threadIdx.x;
    __shared__ float Ws[16][17], Ps[16][17];
    float acc = 0.f;
    for (int p0 = 0; p0 < PP; p0 += 16) {
        Ws[ty][tx] = W1[(o0 + ty) * PP + p0 + tx];
        Ps[ty][tx] = pooled[((size_t)b * CH + (c0 + ty)) * PP + p0 + tx];
        __syncthreads();
#pragma unroll
        for (int p = 0; p < 16; ++p) acc += Ws[ty][p] * Ps[tx][p];
        __syncthreads();
    }
    int c = c0 + tx, o = o0 + ty;
    Mb16[(((size_t)b * 32 + (c >> 3)) * 256 + o) * 8 + (c & 7)] = f2bfu(acc);
}

// ---------------------------------------------------------------------------
// W2 repack: W2r2[s][cb][o][ci] = bf16(W2[o][cb*8+ci][s])
__global__ void repack_w2_k(const float* __restrict__ W2, ushortT* __restrict__ W2r2)
{
    int e = blockIdx.x * 256 + threadIdx.x;     // 589824 total, exact
    int ci = e & 7, o = (e >> 3) & 255, cb = (e >> 11) & 31, s = e >> 16;
    int c = cb * 8 + ci;
    W2r2[e] = f2bfu(W2[((size_t)o * 256 + c) * 9 + s]);
}

// ---------------------------------------------------------------------------
// zero only the pad border of apad. grid (nslots), 256 threads
__global__ void zborder_k(uint4* __restrict__ apad)
{
    int bl = blockIdx.x;
    uint4* apC = apad + (size_t)bl * APAD_CHUNKS;
    uint4 z; z.x = 0; z.y = 0; z.z = 0; z.w = 0;
    for (int e = threadIdx.x; e < 3136; e += 256) {       // rows 0 and 97
        apC[e] = z;
        apC[(size_t)97 * 32 * 98 + e] = z;
    }
    for (int e = threadIdx.x; e < 3072; e += 256) {       // cols 0 and 97
        int row = 1 + (e >> 5), cb = e & 31;
        size_t base = (size_t)(row * 32 + cb) * 98;
        apC[base] = z;
        apC[base + 97] = z;
    }
}

// ---------------------------------------------------------------------------
// y1 GEMM via MFMA, 2-phase double-buffered staging (r6-exact).
// Block 128o x 128hw, 4 waves (2x2). grid (72, 2, nb)
__global__ __launch_bounds__(256, 4) void gemmYm_k(const ushortT* __restrict__ Mb16,
                                                   const ushortT* __restrict__ fpack,
                                                   const float* __restrict__ rnorm,
                                                   ushortT* __restrict__ apad, int b0)
{
    int bl = blockIdx.z, bg = b0 + bl;
    int hw0 = blockIdx.x * 128;
    int o0 = blockIdx.y * 128;
    int tid = threadIdx.x, wave = tid >> 6, lane = tid & 63;
    int wm = wave >> 1, wn = wave & 1;
    int lr = lane & 15, kb = lane >> 4;

    __shared__ __align__(16) char smem[33280];   // 2x16KB stage bufs; T overlays

    const uint4* MbC = (const uint4*)Mb16 + (size_t)bg * 32 * 256;
    const uint4* fpC = (const uint4*)fpack + (size_t)bg * 32 * HWSZ;

    f32x4 acc[4][4] = {};

    auto STAGE = [&](int buf, int s) {
        int cb0 = s * 4;
        uint4* A = (uint4*)smem + (size_t)buf * 1024;
        uint4* B = A + 512;
#pragma unroll
        for (int i = 0; i < 2; ++i) {
            int e = tid + i * 256;
            int kk = e >> 7, j = e & 127;
            gload16(MbC + (size_t)(cb0 + kk) * 256 + o0 + j, A + e);
            gload16(fpC + (size_t)(cb0 + kk) * HWSZ + hw0 + j, B + e);
        }
    };

    STAGE(0, 0);
    for (int s = 0; s < 8; ++s) {
        int buf = s & 1;
        __syncthreads();                     // drains prev stage (vmcnt0+barrier)
        if (s < 7) STAGE(buf ^ 1, s + 1);
        const bf16x8* AsV = (const bf16x8*)(smem + (size_t)buf * 16384);
        const bf16x8* BsV = AsV + 512;
        bf16x8 af[4], bfv[4];
#pragma unroll
        for (int mf = 0; mf < 4; ++mf) af[mf] = AsV[kb * 128 + wm * 64 + mf * 16 + lr];
#pragma unroll
        for (int nf = 0; nf < 4; ++nf) bfv[nf] = BsV[kb * 128 + wn * 64 + nf * 16 + lr];
#pragma unroll
        for (int mf = 0; mf < 4; ++mf)
#pragma unroll
            for (int nf = 0; nf < 4; ++nf)
                acc[mf][nf] = __builtin_amdgcn_mfma_f32_16x16x32_bf16(af[mf], bfv[nf], acc[mf][nf], 0, 0, 0);
    }
    __syncthreads();

    float rn[4];
#pragma unroll
    for (int nf = 0; nf < 4; ++nf)
        rn[nf] = rnorm[(size_t)bg * HWSZ + hw0 + wn * 64 + nf * 16 + lr];

    // transpose through LDS: T[hw_local][o_local], stride 130
    ushortT* T = (ushortT*)smem;
#pragma unroll
    for (int mf = 0; mf < 4; ++mf)
#pragma unroll
        for (int nf = 0; nf < 4; ++nf)
#pragma unroll
            for (int r = 0; r < 4; ++r)
                T[(wn * 64 + nf * 16 + lr) * 130 + wm * 64 + mf * 16 + kb * 4 + r] =
                    f2bfu(acc[mf][nf][r] * rn[nf]);
    __syncthreads();

    uint4* apC = (uint4*)apad + (size_t)bl * APAD_CHUNKS;
    int ob0 = blockIdx.y * 16;
#pragma unroll
    for (int i = 0; i < 8; ++i) {
        int e = tid + i * 256;
        int hw_l = e >> 4, ob = e & 15;
        uint4 v = *(uint4*)&T[hw_l * 130 + ob * 8];
        int hw = hw0 + hw_l;
        int h = hw / 96, w = hw - h * 96;
        apC[(size_t)((h + 1) * 32 + ob0 + ob) * 98 + (w + 1)] = v;
    }
}

// ---------------------------------------------------------------------------
// instance-norm stats from apad (bf16): per (bl, ob) block -> 8 o's (r6-exact)
__global__ void instats2_k(const ushortT* __restrict__ apad, float* __restrict__ mu,
                           float* __restrict__ istd)
{
    int ob = blockIdx.x, bl = blockIdx.y;
    const uint4* apC = (const uint4*)apad + (size_t)bl * APAD_CHUNKS;
    float s[8] = {}, s2[8] = {};
    for (int e = threadIdx.x; e < HWSZ; e += 256) {
        int row = e / 96;
        int w = e - row * 96;
        uint4 v = apC[(size_t)((row + 1) * 32 + ob) * 98 + w + 1];
        const ushortT* u = (const ushortT*)&v;
#pragma unroll
        for (int k = 0; k < 8; ++k) {
            float f = bfu2f(u[k]);
            s[k] += f; s2[k] += f * f;
        }
    }
#pragma unroll
    for (int off = 32; off > 0; off >>= 1) {
#pragma unroll
        for (int k = 0; k < 8; ++k) {
            s[k]  += __shfl_down(s[k],  off, 64);
            s2[k] += __shfl_down(s2[k], off, 64);
        }
    }
    __shared__ float sh[4][16];
    int wid = threadIdx.x >> 6;
    if ((threadIdx.x & 63) == 0) {
#pragma unroll
        for (int k = 0; k < 8; ++k) { sh[wid][k] = s[k]; sh[wid][8 + k] = s2[k]; }
    }
    __syncthreads();
    if (threadIdx.x < 8) {
        int k = threadIdx.x;
        float S  = sh[0][k] + sh[1][k] + sh[2][k] + sh[3][k];
        float S2 = sh[0][8 + k] + sh[1][8 + k] + sh[2][8 + k] + sh[3][8 + k];
        float m   = S * (1.0f / HWSZ);
        float var = S2 * (1.0f / HWSZ) - m * m;
        if (var < 0.f) var = 0.f;
        mu[bl * 256 + ob * 8 + k]   = m;
        istd[bl * 256 + ob * 8 + k] = rsqrtf(var + 1e-5f);
    }
}

// ---------------------------------------------------------------------------
// in-place normalize+relu on apad interior. grid (96, nb)
__global__ void nr_k(ushortT* __restrict__ apad, const float* __restrict__ mu,
                     const float* __restrict__ istd)
{
    int row = blockIdx.x + 1, bl = blockIdx.y;
    __shared__ float smu[256], sis[256];
    smu[threadIdx.x] = mu[bl * 256 + threadIdx.x];
    sis[threadIdx.x] = istd[bl * 256 + threadIdx.x];
    __syncthreads();
    uint4* apC = (uint4*)apad + (size_t)bl * APAD_CHUNKS + (size_t)row * 32 * 98;
    for (int e = threadIdx.x; e < 3072; e += 256) {
        int ob = e / 96;
        int w = e - ob * 96 + 1;
        uint4 v = apC[(size_t)ob * 98 + w];
        ushortT* u = (ushortT*)&v;
#pragma unroll
        for (int k = 0; k < 8; ++k) {
            float f = (bfu2f(u[k]) - smu[ob * 8 + k]) * sis[ob * 8 + k];
            u[k] = f2bfu(f > 0.f ? f : 0.f);
        }
        apC[(size_t)ob * 98 + w] = v;
    }
}

// ---------------------------------------------------------------------------
// 3x3 conv implicit-GEMM MFMA v10: 4-row tile + FULL dbuf + 8 waves.
// r7's dbuf failed at 4 waves (1 wave/SIMD: LDS latency exposed). Here the
// same 149.5 KB dbuf runs with 8 waves = 2 waves/SIMD: each output row is
// computed by TWO waves (half = w&1 owns 48 of 96 cols, acc[4][3]).
// Staging volume unchanged (915 MB/feat); dbuf rate 8.5 TB/s (r5-measured)
// -> ~108 us/feat vs single-buf 6.1 TB/s (~148 us).
// XCD swizzle (swz=1, nb==16): each XCD owns 2 batches -> B-rows L2-reused
// across the 4 o-tiles; working set/XCD ~ 2 apads streamed.
// grid (24, 4, nb) = 1536 blocks = 6 rounds at 1 block/CU.
__global__ __launch_bounds__(512, 1) void conv3m10_k(const ushortT* __restrict__ apad,
                                                     const ushortT* __restrict__ W2r2,
                                                     const float* __restrict__ b2,
                                                     float* __restrict__ out, int swz)
{
    int ht, ot, bl;
    if (swz) {
        int lin = blockIdx.x + 24 * (blockIdx.y + 4 * blockIdx.z);
        int xcd = lin & 7, i = lin >> 3;          // i in [0,192)
        int second = (i >= 96) ? 1 : 0;
        bl = 2 * xcd + second;
        int w = i - second * 96;                  // [0,96)
        ot = w / 24; ht = w - ot * 24;
    } else {
        ht = blockIdx.x; ot = blockIdx.y; bl = blockIdx.z;
    }
    int h0 = ht * 4;
    int o0 = ot * 64;
    int tid = threadIdx.x;
    int wave = tid >> 6, lane = tid & 63;
    int row = wave >> 1, half = wave & 1;   // wave = (output row, w-half)
    int lr = lane & 15, kb = lane >> 4;

    __shared__ __align__(16) uint4 AsC[2][2304];   // [s9][kk4][o64]
    __shared__ __align__(16) uint4 BsC[2][2368];   // [row6][kk4][w98], 2352 used

    const uint4* apadC = (const uint4*)apad + (size_t)bl * APAD_CHUNKS;
    const uint4* w2C   = (const uint4*)W2r2;

    f32x4 acc[4][3] = {};

    auto STAGE = [&](int buf, int ci) {
        int cb0 = ci * 4;
#pragma unroll
        for (int i = 0; i < 5; ++i) {       // A: 2304 chunks, guarded
            int e = tid + i * 512;
            if (e < 2304) {
                int o = e & 63, kk = (e >> 6) & 3, s = e >> 8;
                gload16(w2C + (size_t)(s * 32 + cb0 + kk) * 256 + o0 + o,
                        &AsC[buf][e]);
            }
        }
#pragma unroll
        for (int i = 0; i < 5; ++i) {       // B: 2352 chunks, guarded
            int e = tid + i * 512;
            if (e < 2352) {
                int w = e % 98, r = e / 98;
                int kk = r & 3, rr = r >> 2;      // apad row h0+rr, rr<6
                gload16(apadC + (size_t)((h0 + rr) * 32 + cb0 + kk) * 98 + w,
                        &BsC[buf][e]);
            }
        }
    };

    STAGE(0, 0);
    for (int ci = 0; ci < 8; ++ci) {
        int buf = ci & 1;
        __syncthreads();                    // drains stage(buf); orders buf^1 reads
        if (ci < 7) STAGE(buf ^ 1, ci + 1);
        const bf16x8* AsV = (const bf16x8*)&AsC[buf][0];
        const bf16x8* BsV = (const bf16x8*)&BsC[buf][0];
#pragma unroll
        for (int kh = 0; kh < 3; ++kh) {
#pragma unroll
            for (int kw = 0; kw < 3; ++kw) {
                int s = kh * 3 + kw;
                bf16x8 af[4];
#pragma unroll
                for (int mf = 0; mf < 4; ++mf)
                    af[mf] = AsV[(s * 4 + kb) * 64 + mf * 16 + lr];
#pragma unroll
                for (int nf = 0; nf < 3; ++nf) {
                    bf16x8 bfr = BsV[((row + kh) * 4 + kb) * 98
                                     + half * 48 + nf * 16 + lr + kw];
#pragma unroll
                    for (int mf = 0; mf < 4; ++mf)
                        acc[mf][nf] = __builtin_amdgcn_mfma_f32_16x16x32_bf16(af[mf], bfr, acc[mf][nf], 0, 0, 0);
                }
            }
        }
    }

    // epilogue: wave's output row h0+row, cols half*48 + nf*16+lr
    int h = h0 + row;
    float* obase = out + (size_t)bl * FCH * HWSZ + (size_t)h * WW + half * 48;
#pragma unroll
    for (int mf = 0; mf < 4; ++mf) {
#pragma unroll
        for (int r = 0; r < 4; ++r) {
            int o = o0 + mf * 16 + kb * 4 + r;
            float bias = b2[o];
            float* orow = obase + (size_t)o * HWSZ;
#pragma unroll
            for (int nf = 0; nf < 3; ++nf)
                orow[nf * 16 + lr] = acc[mf][nf][r] + bias;
        }
    }
}

// ---------------------------------------------------------------------------
extern "C" void kernel_launch(void* const* d_in, const int* in_sizes, int n_in,
                              void* d_out, int out_size, void* d_ws, size_t ws_size,
                              hipStream_t stream)
{
    const float* Fir  = (const float*)d_in[0];
    const float* Fvis = (const float*)d_in[1];
    const float* W1   = (const float*)d_in[2];
    // d_in[3] = b1: canceled exactly by InstanceNorm -> unused
    const float* W2   = (const float*)d_in[4];
    const float* b2   = (const float*)d_in[5];
    float* out = (float*)d_out;

    char* w = (char*)d_ws;
    const size_t poolB = (size_t)BATCH * CH * PP * 4;        // 4 MB
    const size_t MbB   = (size_t)BATCH * 32 * 256 * 8 * 2;   // 2 MB
    const size_t rnB   = (size_t)BATCH * HWSZ * 4;           // 0.56 MB
    const size_t stB   = (size_t)BATCH * FCH * 4;            // 16 KB
    const size_t w2rB  = (size_t)9 * 32 * 256 * 8 * 2;       // 1.125 MB
    const size_t fpB   = (size_t)BATCH * 32 * HWSZ * 8 * 2;  // 75.5 MB

    size_t off = 0;
    float*   pooled = (float*)(w + off);   off += poolB;
    ushortT* Mb16   = (ushortT*)(w + off); off += MbB;
    float*   rnorm  = (float*)(w + off);   off += rnB;
    float*   mu     = (float*)(w + off);   off += stB;
    float*   istd   = (float*)(w + off);   off += stB;
    ushortT* W2r2   = (ushortT*)(w + off); off += w2rB;
    ushortT* fpack  = (ushortT*)(w + off); off += fpB;
    const size_t fixed = off;

    const size_t apadB = (size_t)APAD_ELEMS * 2;             // 4.92 MB / slot
    size_t avail = ws_size > fixed ? ws_size - fixed : 0;
    int NB = (int)(avail / apadB);
    if (NB > BATCH) NB = BATCH;
    if (NB < 1) NB = 1;
    ushortT* apad = (ushortT*)(w + fixed);

    repack_w2_k<<<2304, 256, 0, stream>>>(W2, W2r2);
    zborder_k<<<NB, 256, 0, stream>>>((uint4*)apad);

    for (int f = 0; f < 2; ++f) {
        const float* feat = (f == 0) ? Fir : Fvis;   // IR first in output
        float* o_ = out + (size_t)f * BATCH * FCH * HWSZ;

        fpack_k<<<dim3(36, BATCH), 256, 0, stream>>>(feat, fpack, rnorm);
        pool16b_k<<<dim3(32, BATCH), 256, 0, stream>>>(fpack, pooled);
        gemmM_k<<<dim3(16, 16, BATCH), dim3(16, 16), 0, stream>>>(W1, pooled, Mb16);

        for (int b0 = 0; b0 < BATCH; b0 += NB) {
            int nb = BATCH - b0 < NB ? BATCH - b0 : NB;
            gemmYm_k<<<dim3(72, 2, nb), 256, 0, stream>>>(Mb16, fpack, rnorm, apad, b0);
            instats2_k<<<dim3(32, nb), 256, 0, stream>>>(apad, mu, istd);
            nr_k<<<dim3(96, nb), 256, 0, stream>>>(apad, mu, istd);
            conv3m10_k<<<dim3(24, 4, nb), 512, 0, stream>>>(apad, W2r2, b2,
                                                            o_ + (size_t)b0 * FCH * HWSZ,
                                                            nb == 16 ? 1 : 0);
        }
    }
}

// Round 12
// 690.228 us; speedup vs baseline: 1.0020x; 1.0020x over previous
//
#include <hip/hip_runtime.h>
#include <hip/hip_bf16.h>

#define BATCH 16
#define CH    256
#define HH    96
#define WW    96
#define HWSZ  9216     // 96*96
#define FCH   256
#define PP    256      // 16*16 pooled positions

typedef float f32x4 __attribute__((ext_vector_type(4)));
typedef short bf16x8 __attribute__((ext_vector_type(8)));
typedef unsigned short ushortT;

#define APAD_ELEMS 2458624   // 98*32*98*8 ushorts per batch
#define APAD_CHUNKS 307328   // uint4 chunks per batch

__device__ __forceinline__ void gload16(const void* g, void* l) {
    __builtin_amdgcn_global_load_lds((const __attribute__((address_space(1))) void*)g,
                                     (__attribute__((address_space(3))) void*)l, 16, 0, 0);
}
__device__ __forceinline__ float bfu2f(ushortT u) {
    return __uint_as_float(((unsigned)u) << 16);
}
__device__ __forceinline__ ushortT f2bfu(float f) {
    __hip_bfloat16 hb = __float2bfloat16(f);
    return *reinterpret_cast<ushortT*>(&hb);
}

// ---------------------------------------------------------------------------
// fused: pack feat -> bf16 chunked [b][cb=32][hw][8ci]  +  rnorm[b,hw]
__global__ void fpack_k(const float* __restrict__ feat, ushortT* __restrict__ fpack,
                        float* __restrict__ rnorm)
{
    int b = blockIdx.y;
    int hw = blockIdx.x * 256 + threadIdx.x;
    const float* src = feat + (size_t)b * CH * HWSZ + hw;
    uint4* dst = (uint4*)fpack + (size_t)b * 32 * HWSZ + hw;
    float ss = 0.f;
    for (int cb = 0; cb < 32; ++cb) {
        union { ushortT u[8]; uint4 v; } pk;
#pragma unroll
        for (int i = 0; i < 8; ++i) {
            float v = src[(size_t)(cb * 8 + i) * HWSZ];
            ss += v * v;
            pk.u[i] = f2bfu(v);
        }
        dst[(size_t)cb * HWSZ] = pk.v;
    }
    rnorm[b * HWSZ + hw] = 1.0f / fmaxf(sqrtf(ss), 1e-12f);
}

// ---------------------------------------------------------------------------
// 6x6 average pool from fpack (bf16, L3-resident): grid (32 cb, B), 256 thr
__global__ void pool16b_k(const ushortT* __restrict__ fpack, float* __restrict__ pooled)
{
    int cb = blockIdx.x, b = blockIdx.y;
    const uint4* fp = (const uint4*)fpack + ((size_t)b * 32 + cb) * HWSZ;
    int t = threadIdx.x;
    int pr = t >> 4, pc = t & 15;
    float s[8] = {};
#pragma unroll
    for (int i = 0; i < 6; ++i) {
#pragma unroll
        for (int j = 0; j < 6; ++j) {
            uint4 v = fp[(pr * 6 + i) * WW + pc * 6 + j];
            const ushortT* u = (const ushortT*)&v;
#pragma unroll
            for (int k = 0; k < 8; ++k) s[k] += bfu2f(u[k]);
        }
    }
#pragma unroll
    for (int k = 0; k < 8; ++k)
        pooled[((size_t)b * CH + cb * 8 + k) * PP + t] = s[k] * (1.0f / 36.0f);
}

// ---------------------------------------------------------------------------
// M[b,o,c] = sum_p W1[o,p] * pooled[b,c,p]  (f32 acc) -> bf16 packed
__global__ void gemmM_k(const float* __restrict__ W1, const float* __restrict__ pooled,
                        ushortT* __restrict__ Mb16)
{
    int b = blockIdx.z;
    int o0 = blockIdx.y * 16, c0 = blockIdx.x * 16;
    int ty = threadIdx.y, tx = threadIdx.x;
    __shared__ float Ws[16][17], Ps[16][17];
    float acc = 0.f;
    for (int p0 = 0; p0 < PP; p0 += 16) {
        Ws[ty][tx] = W1[(o0 + ty) * PP + p0 + tx];
        Ps[ty][tx] = pooled[((size_t)b * CH + (c0 + ty)) * PP + p0 + tx];
        __syncthreads();
#pragma unroll
        for (int p = 0; p < 16; ++p) acc += Ws[ty][p] * Ps[tx][p];
        __syncthreads();
    }
    int c = c0 + tx, o = o0 + ty;
    Mb16[(((size_t)b * 32 + (c >> 3)) * 256 + o) * 8 + (c & 7)] = f2bfu(acc);
}

// ---------------------------------------------------------------------------
// W2 repack: W2r2[s][cb][o][ci] = bf16(W2[o][cb*8+ci][s])
__global__ void repack_w2_k(const float* __restrict__ W2, ushortT* __restrict__ W2r2)
{
    int e = blockIdx.x * 256 + threadIdx.x;     // 589824 total, exact
    int ci = e & 7, o = (e >> 3) & 255, cb = (e >> 11) & 31, s = e >> 16;
    int c = cb * 8 + ci;
    W2r2[e] = f2bfu(W2[((size_t)o * 256 + c) * 9 + s]);
}

// ---------------------------------------------------------------------------
// zero only the pad border of apad. grid (nslots), 256 threads
__global__ void zborder_k(uint4* __restrict__ apad)
{
    int bl = blockIdx.x;
    uint4* apC = apad + (size_t)bl * APAD_CHUNKS;
    uint4 z; z.x = 0; z.y = 0; z.z = 0; z.w = 0;
    for (int e = threadIdx.x; e < 3136; e += 256) {       // rows 0 and 97
        apC[e] = z;
        apC[(size_t)97 * 32 * 98 + e] = z;
    }
    for (int e = threadIdx.x; e < 3072; e += 256) {       // cols 0 and 97
        int row = 1 + (e >> 5), cb = e & 31;
        size_t base = (size_t)(row * 32 + cb) * 98;
        apC[base] = z;
        apC[base + 97] = z;
    }
}

// ---------------------------------------------------------------------------
// y1 GEMM via MFMA, 2-phase double-buffered staging (r6-exact epilogue)
// + fused IN-stat partials (r9-verified). Block 128o x 128hw, 4 waves (2x2).
// grid (72, 2, nb). Partials ps/ps2[bl][o 256][144], col = hwblk*2+wn.
__global__ __launch_bounds__(256, 4) void gemmYm_k(const ushortT* __restrict__ Mb16,
                                                   const ushortT* __restrict__ fpack,
                                                   const float* __restrict__ rnorm,
                                                   ushortT* __restrict__ apad,
                                                   float* __restrict__ ps,
                                                   float* __restrict__ ps2, int b0)
{
    int bl = blockIdx.z, bg = b0 + bl;
    int hw0 = blockIdx.x * 128;
    int o0 = blockIdx.y * 128;
    int tid = threadIdx.x, wave = tid >> 6, lane = tid & 63;
    int wm = wave >> 1, wn = wave & 1;
    int lr = lane & 15, kb = lane >> 4;

    __shared__ __align__(16) char smem[33280];   // 2x16KB stage bufs; T overlays

    const uint4* MbC = (const uint4*)Mb16 + (size_t)bg * 32 * 256;
    const uint4* fpC = (const uint4*)fpack + (size_t)bg * 32 * HWSZ;

    f32x4 acc[4][4] = {};

    auto STAGE = [&](int buf, int s) {
        int cb0 = s * 4;
        uint4* A = (uint4*)smem + (size_t)buf * 1024;
        uint4* B = A + 512;
#pragma unroll
        for (int i = 0; i < 2; ++i) {
            int e = tid + i * 256;
            int kk = e >> 7, j = e & 127;
            gload16(MbC + (size_t)(cb0 + kk) * 256 + o0 + j, A + e);
            gload16(fpC + (size_t)(cb0 + kk) * HWSZ + hw0 + j, B + e);
        }
    };

    STAGE(0, 0);
    for (int s = 0; s < 8; ++s) {
        int buf = s & 1;
        __syncthreads();                     // drains prev stage (vmcnt0+barrier)
        if (s < 7) STAGE(buf ^ 1, s + 1);
        const bf16x8* AsV = (const bf16x8*)(smem + (size_t)buf * 16384);
        const bf16x8* BsV = AsV + 512;
        bf16x8 af[4], bfv[4];
#pragma unroll
        for (int mf = 0; mf < 4; ++mf) af[mf] = AsV[kb * 128 + wm * 64 + mf * 16 + lr];
#pragma unroll
        for (int nf = 0; nf < 4; ++nf) bfv[nf] = BsV[kb * 128 + wn * 64 + nf * 16 + lr];
#pragma unroll
        for (int mf = 0; mf < 4; ++mf)
#pragma unroll
            for (int nf = 0; nf < 4; ++nf)
                acc[mf][nf] = __builtin_amdgcn_mfma_f32_16x16x32_bf16(af[mf], bfv[nf], acc[mf][nf], 0, 0, 0);
    }
    __syncthreads();

    float rn[4];
#pragma unroll
    for (int nf = 0; nf < 4; ++nf)
        rn[nf] = rnorm[(size_t)bg * HWSZ + hw0 + wn * 64 + nf * 16 + lr];

    // fused IN-stat partials (r9-verified): per (mf,r) sum over this wave's
    // 64 hw cells (4 nf x 16 lr), reduced via 16-lane shfl.
    {
        float sA[4][4], sB[4][4];
#pragma unroll
        for (int mf = 0; mf < 4; ++mf)
#pragma unroll
            for (int r = 0; r < 4; ++r) {
                float s1 = 0.f, s2 = 0.f;
#pragma unroll
                for (int nf = 0; nf < 4; ++nf) {
                    float v = acc[mf][nf][r] * rn[nf];
                    s1 += v; s2 += v * v;
                }
#pragma unroll
                for (int off = 8; off > 0; off >>= 1) {
                    s1 += __shfl_down(s1, off, 16);
                    s2 += __shfl_down(s2, off, 16);
                }
                sA[mf][r] = s1; sB[mf][r] = s2;
            }
        if (lr == 0) {
            int col = blockIdx.x * 2 + wn;
#pragma unroll
            for (int mf = 0; mf < 4; ++mf)
#pragma unroll
                for (int r = 0; r < 4; ++r) {
                    int og = o0 + wm * 64 + mf * 16 + kb * 4 + r;
                    size_t idx = ((size_t)bl * 256 + og) * 144 + col;
                    ps[idx]  = sA[mf][r];
                    ps2[idx] = sB[mf][r];
                }
        }
    }

    // transpose through LDS: T[hw_local][o_local], stride 130 (r6-exact)
    ushortT* T = (ushortT*)smem;
#pragma unroll
    for (int mf = 0; mf < 4; ++mf)
#pragma unroll
        for (int nf = 0; nf < 4; ++nf)
#pragma unroll
            for (int r = 0; r < 4; ++r)
                T[(wn * 64 + nf * 16 + lr) * 130 + wm * 64 + mf * 16 + kb * 4 + r] =
                    f2bfu(acc[mf][nf][r] * rn[nf]);
    __syncthreads();

    uint4* apC = (uint4*)apad + (size_t)bl * APAD_CHUNKS;
    int ob0 = blockIdx.y * 16;
#pragma unroll
    for (int i = 0; i < 8; ++i) {
        int e = tid + i * 256;
        int hw_l = e >> 4, ob = e & 15;     // r6 order (bank-conflict-free T read)
        uint4 v = *(uint4*)&T[hw_l * 130 + ob * 8];
        int hw = hw0 + hw_l;
        int h = hw / 96, w = hw - h * 96;
        apC[(size_t)((h + 1) * 32 + ob0 + ob) * 98 + (w + 1)] = v;
    }
}

// ---------------------------------------------------------------------------
// finalize IN stats: mu/istd from partials. grid (nb), 256 thr (one per o)
__global__ void finstats_k(const float* __restrict__ ps, const float* __restrict__ ps2,
                           float* __restrict__ mu, float* __restrict__ istd)
{
    int bl = blockIdx.x, o = threadIdx.x;
    const float* p1 = ps  + ((size_t)bl * 256 + o) * 144;
    const float* p2 = ps2 + ((size_t)bl * 256 + o) * 144;
    float S = 0.f, S2 = 0.f;
    for (int i = 0; i < 144; ++i) { S += p1[i]; S2 += p2[i]; }
    float m   = S * (1.0f / HWSZ);
    float var = S2 * (1.0f / HWSZ) - m * m;
    if (var < 0.f) var = 0.f;
    mu[bl * 256 + o]   = m;
    istd[bl * 256 + o] = rsqrtf(var + 1e-5f);
}

// ---------------------------------------------------------------------------
// in-place normalize+relu on apad interior. grid (96, nb)
__global__ void nr_k(ushortT* __restrict__ apad, const float* __restrict__ mu,
                     const float* __restrict__ istd)
{
    int row = blockIdx.x + 1, bl = blockIdx.y;
    __shared__ float smu[256], sis[256];
    smu[threadIdx.x] = mu[bl * 256 + threadIdx.x];
    sis[threadIdx.x] = istd[bl * 256 + threadIdx.x];
    __syncthreads();
    uint4* apC = (uint4*)apad + (size_t)bl * APAD_CHUNKS + (size_t)row * 32 * 98;
    for (int e = threadIdx.x; e < 3072; e += 256) {
        int ob = e / 96;
        int w = e - ob * 96 + 1;
        uint4 v = apC[(size_t)ob * 98 + w];
        ushortT* u = (ushortT*)&v;
#pragma unroll
        for (int k = 0; k < 8; ++k) {
            float f = (bfu2f(u[k]) - smu[ob * 8 + k]) * sis[ob * 8 + k];
            u[k] = f2bfu(f > 0.f ? f : 0.f);
        }
        apC[(size_t)ob * 98 + w] = v;
    }
}

// ---------------------------------------------------------------------------
// 3x3 conv implicit-GEMM MFMA (r6-EXACT conv3m4): 4 output rows per block.
// Block: 64 o x 4 rows x 96 w; wave = its output row; acc[4][6].
// Per c-iter: stage A for ALL 9 taps (2304 chunks) + B as 6 contiguous rows
// (2352 chunks + clamp-pad tail into BsC[2560]). LDS 77824 B, 2 blocks/CU.
// Known-best after 6 conv variants: LDS-read + MFMA pipes serialize (sum
// model ~14000 cyc/ci-pair); dbuf/more-waves/A-in-regs all regressed.
// grid (24, 4, nb) = 1536 blocks = 3 exact rounds at 2 blocks/CU.
__global__ __launch_bounds__(256, 2) void conv3m4_k(const ushortT* __restrict__ apad,
                                                    const ushortT* __restrict__ W2r2,
                                                    const float* __restrict__ b2,
                                                    float* __restrict__ out)
{
    int h0 = blockIdx.x * 4;
    int o0 = blockIdx.y * 64;
    int bl = blockIdx.z;
    int tid = threadIdx.x;
    int wave = tid >> 6, lane = tid & 63;   // wave = output row within tile
    int lr = lane & 15, kb = lane >> 4;

    __shared__ __align__(16) uint4 AsC[2304];   // [s9][kk4][o64]
    __shared__ __align__(16) uint4 BsC[2560];   // [row6][kk4][w98], 2352 used

    const uint4* apadC = (const uint4*)apad + (size_t)bl * APAD_CHUNKS;
    const uint4* w2C   = (const uint4*)W2r2;
    const bf16x8* AsV = (const bf16x8*)AsC;
    const bf16x8* BsV = (const bf16x8*)BsC;

    f32x4 acc[4][6] = {};

    for (int ci = 0; ci < 8; ++ci) {
        int cb0 = ci * 4;
        __syncthreads();                    // all waves done reading prev iter
#pragma unroll
        for (int i = 0; i < 9; ++i) {       // A: 2304 chunks exact
            int e = tid + i * 256;
            int o = e & 63, kk = (e >> 6) & 3, s = e >> 8;
            gload16(w2C + (size_t)(s * 32 + cb0 + kk) * 256 + o0 + o, &AsC[e]);
        }
#pragma unroll
        for (int i = 0; i < 10; ++i) {      // B: 2352 real + 208 pad writes
            int e = tid + i * 256;
            int se = e < 2352 ? e : e - 256;  // clamp SOURCE only; dest padded
            int w = se % 98, r = se / 98;
            int kk = r & 3, row = r >> 2;     // apad row h0+row, row<6
            gload16(apadC + (size_t)((h0 + row) * 32 + cb0 + kk) * 98 + w, &BsC[e]);
        }
        __syncthreads();                    // vmcnt(0) drain: stage ready
#pragma unroll
        for (int kh = 0; kh < 3; ++kh) {
#pragma unroll
            for (int kw = 0; kw < 3; ++kw) {
                int s = kh * 3 + kw;
                bf16x8 af[4];
#pragma unroll
                for (int mf = 0; mf < 4; ++mf)
                    af[mf] = AsV[(s * 4 + kb) * 64 + mf * 16 + lr];
#pragma unroll
                for (int nf = 0; nf < 6; ++nf) {
                    bf16x8 bfr = BsV[((wave + kh) * 4 + kb) * 98 + nf * 16 + lr + kw];
#pragma unroll
                    for (int mf = 0; mf < 4; ++mf)
                        acc[mf][nf] = __builtin_amdgcn_mfma_f32_16x16x32_bf16(af[mf], bfr, acc[mf][nf], 0, 0, 0);
                }
            }
        }
    }

    // epilogue: wave's output row h0+wave; C row(o)=mf*16+kb*4+r, col(w)=nf*16+lr
    int h = h0 + wave;
    float* obase = out + (size_t)bl * FCH * HWSZ + (size_t)h * WW;
#pragma unroll
    for (int mf = 0; mf < 4; ++mf) {
#pragma unroll
        for (int r = 0; r < 4; ++r) {
            int o = o0 + mf * 16 + kb * 4 + r;
            float bias = b2[o];
            float* orow = obase + (size_t)o * HWSZ;
#pragma unroll
            for (int nf = 0; nf < 6; ++nf)
                orow[nf * 16 + lr] = acc[mf][nf][r] + bias;
        }
    }
}

// ---------------------------------------------------------------------------
extern "C" void kernel_launch(void* const* d_in, const int* in_sizes, int n_in,
                              void* d_out, int out_size, void* d_ws, size_t ws_size,
                              hipStream_t stream)
{
    const float* Fir  = (const float*)d_in[0];
    const float* Fvis = (const float*)d_in[1];
    const float* W1   = (const float*)d_in[2];
    // d_in[3] = b1: canceled exactly by InstanceNorm -> unused
    const float* W2   = (const float*)d_in[4];
    const float* b2   = (const float*)d_in[5];
    float* out = (float*)d_out;

    char* w = (char*)d_ws;
    const size_t poolB = (size_t)BATCH * CH * PP * 4;        // 4 MB
    const size_t MbB   = (size_t)BATCH * 32 * 256 * 8 * 2;   // 2 MB
    const size_t rnB   = (size_t)BATCH * HWSZ * 4;           // 0.56 MB
    const size_t stB   = (size_t)BATCH * FCH * 4;            // 16 KB
    const size_t w2rB  = (size_t)9 * 32 * 256 * 8 * 2;       // 1.125 MB
    const size_t psB   = (size_t)BATCH * 256 * 144 * 4;      // 2.36 MB
    const size_t fpB   = (size_t)BATCH * 32 * HWSZ * 8 * 2;  // 75.5 MB

    size_t off = 0;
    float*   pooled = (float*)(w + off);   off += poolB;
    ushortT* Mb16   = (ushortT*)(w + off); off += MbB;
    float*   rnorm  = (float*)(w + off);   off += rnB;
    float*   mu     = (float*)(w + off);   off += stB;
    float*   istd   = (float*)(w + off);   off += stB;
    ushortT* W2r2   = (ushortT*)(w + off); off += w2rB;
    float*   ps     = (float*)(w + off);   off += psB;
    float*   ps2    = (float*)(w + off);   off += psB;
    ushortT* fpack  = (ushortT*)(w + off); off += fpB;
    const size_t fixed = off;

    const size_t apadB = (size_t)APAD_ELEMS * 2;             // 4.92 MB / slot
    size_t avail = ws_size > fixed ? ws_size - fixed : 0;
    int NB = (int)(avail / apadB);
    if (NB > BATCH) NB = BATCH;
    if (NB < 1) NB = 1;
    ushortT* apad = (ushortT*)(w + fixed);

    repack_w2_k<<<2304, 256, 0, stream>>>(W2, W2r2);
    zborder_k<<<NB, 256, 0, stream>>>((uint4*)apad);

    for (int f = 0; f < 2; ++f) {
        const float* feat = (f == 0) ? Fir : Fvis;   // IR first in output
        float* o_ = out + (size_t)f * BATCH * FCH * HWSZ;

        fpack_k<<<dim3(36, BATCH), 256, 0, stream>>>(feat, fpack, rnorm);
        pool16b_k<<<dim3(32, BATCH), 256, 0, stream>>>(fpack, pooled);
        gemmM_k<<<dim3(16, 16, BATCH), dim3(16, 16), 0, stream>>>(W1, pooled, Mb16);

        for (int b0 = 0; b0 < BATCH; b0 += NB) {
            int nb = BATCH - b0 < NB ? BATCH - b0 : NB;
            gemmYm_k<<<dim3(72, 2, nb), 256, 0, stream>>>(Mb16, fpack, rnorm, apad,
                                                          ps, ps2, b0);
            finstats_k<<<nb, 256, 0, stream>>>(ps, ps2, mu, istd);
            nr_k<<<dim3(96, nb), 256, 0, stream>>>(apad, mu, istd);
            conv3m4_k<<<dim3(24, 4, nb), 256, 0, stream>>>(apad, W2r2, b2,
                                                           o_ + (size_t)b0 * FCH * HWSZ);
        }
    }
}

// Round 13
// 635.679 us; speedup vs baseline: 1.0879x; 1.0858x over previous
//
#include <hip/hip_runtime.h>
#include <hip/hip_bf16.h>

#define BATCH 16
#define CH    256
#define HH    96
#define WW    96
#define HWSZ  9216     // 96*96
#define FCH   256
#define PP    256      // 16*16 pooled positions

typedef float f32x4 __attribute__((ext_vector_type(4)));
typedef short bf16x8 __attribute__((ext_vector_type(8)));
typedef unsigned short ushortT;

#define APAD_ELEMS 2458624   // 98*32*98*8 ushorts per batch
#define APAD_CHUNKS 307328   // uint4 chunks per batch

__device__ __forceinline__ void gload16(const void* g, void* l) {
    __builtin_amdgcn_global_load_lds((const __attribute__((address_space(1))) void*)g,
                                     (__attribute__((address_space(3))) void*)l, 16, 0, 0);
}
__device__ __forceinline__ float bfu2f(ushortT u) {
    return __uint_as_float(((unsigned)u) << 16);
}
__device__ __forceinline__ ushortT f2bfu(float f) {
    __hip_bfloat16 hb = __float2bfloat16(f);
    return *reinterpret_cast<ushortT*>(&hb);
}

// ---------------------------------------------------------------------------
// fused: pack feat -> bf16 chunked [b][cb=32][hw][8ci]  +  rnorm[b,hw]
__global__ void fpack_k(const float* __restrict__ feat, ushortT* __restrict__ fpack,
                        float* __restrict__ rnorm)
{
    int b = blockIdx.y;
    int hw = blockIdx.x * 256 + threadIdx.x;
    const float* src = feat + (size_t)b * CH * HWSZ + hw;
    uint4* dst = (uint4*)fpack + (size_t)b * 32 * HWSZ + hw;
    float ss = 0.f;
    for (int cb = 0; cb < 32; ++cb) {
        union { ushortT u[8]; uint4 v; } pk;
#pragma unroll
        for (int i = 0; i < 8; ++i) {
            float v = src[(size_t)(cb * 8 + i) * HWSZ];
            ss += v * v;
            pk.u[i] = f2bfu(v);
        }
        dst[(size_t)cb * HWSZ] = pk.v;
    }
    rnorm[b * HWSZ + hw] = 1.0f / fmaxf(sqrtf(ss), 1e-12f);
}

// ---------------------------------------------------------------------------
// 6x6 average pool from fpack (bf16, L3-resident): grid (32 cb, B), 256 thr
__global__ void pool16b_k(const ushortT* __restrict__ fpack, float* __restrict__ pooled)
{
    int cb = blockIdx.x, b = blockIdx.y;
    const uint4* fp = (const uint4*)fpack + ((size_t)b * 32 + cb) * HWSZ;
    int t = threadIdx.x;
    int pr = t >> 4, pc = t & 15;
    float s[8] = {};
#pragma unroll
    for (int i = 0; i < 6; ++i) {
#pragma unroll
        for (int j = 0; j < 6; ++j) {
            uint4 v = fp[(pr * 6 + i) * WW + pc * 6 + j];
            const ushortT* u = (const ushortT*)&v;
#pragma unroll
            for (int k = 0; k < 8; ++k) s[k] += bfu2f(u[k]);
        }
    }
#pragma unroll
    for (int k = 0; k < 8; ++k)
        pooled[((size_t)b * CH + cb * 8 + k) * PP + t] = s[k] * (1.0f / 36.0f);
}

// ---------------------------------------------------------------------------
// M[b,o,c] = sum_p W1[o,p] * pooled[b,c,p]  (f32 acc) -> bf16 packed
__global__ void gemmM_k(const float* __restrict__ W1, const float* __restrict__ pooled,
                        ushortT* __restrict__ Mb16)
{
    int b = blockIdx.z;
    int o0 = blockIdx.y * 16, c0 = blockIdx.x * 16;
    int ty = threadIdx.y, tx = threadIdx.x;
    __shared__ float Ws[16][17], Ps[16][17];
    float acc = 0.f;
    for (int p0 = 0; p0 < PP; p0 += 16) {
        Ws[ty][tx] = W1[(o0 + ty) * PP + p0 + tx];
        Ps[ty][tx] = pooled[((size_t)b * CH + (c0 + ty)) * PP + p0 + tx];
        __syncthreads();
#pragma unroll
        for (int p = 0; p < 16; ++p) acc += Ws[ty][p] * Ps[tx][p];
        __syncthreads();
    }
    int c = c0 + tx, o = o0 + ty;
    Mb16[(((size_t)b * 32 + (c >> 3)) * 256 + o) * 8 + (c & 7)] = f2bfu(acc);
}

// ---------------------------------------------------------------------------
// W2 repack: W2r2[s][cb][o][ci] = bf16(W2[o][cb*8+ci][s])
__global__ void repack_w2_k(const float* __restrict__ W2, ushortT* __restrict__ W2r2)
{
    int e = blockIdx.x * 256 + threadIdx.x;     // 589824 total, exact
    int ci = e & 7, o = (e >> 3) & 255, cb = (e >> 11) & 31, s = e >> 16;
    int c = cb * 8 + ci;
    W2r2[e] = f2bfu(W2[((size_t)o * 256 + c) * 9 + s]);
}

// ---------------------------------------------------------------------------
// zero only the pad border of apad. grid (nslots), 256 threads
__global__ void zborder_k(uint4* __restrict__ apad)
{
    int bl = blockIdx.x;
    uint4* apC = apad + (size_t)bl * APAD_CHUNKS;
    uint4 z; z.x = 0; z.y = 0; z.z = 0; z.w = 0;
    for (int e = threadIdx.x; e < 3136; e += 256) {       // rows 0 and 97
        apC[e] = z;
        apC[(size_t)97 * 32 * 98 + e] = z;
    }
    for (int e = threadIdx.x; e < 3072; e += 256) {       // cols 0 and 97
        int row = 1 + (e >> 5), cb = e & 31;
        size_t base = (size_t)(row * 32 + cb) * 98;
        apC[base] = z;
        apC[base + 97] = z;
    }
}

// ---------------------------------------------------------------------------
// y1 GEMM via MFMA, 2-phase double-buffered staging (exact 512-chunk stages).
// Block 128o x 128hw, 4 waves (2x2). grid (72, 2, nb)
__global__ __launch_bounds__(256, 4) void gemmYm_k(const ushortT* __restrict__ Mb16,
                                                   const ushortT* __restrict__ fpack,
                                                   const float* __restrict__ rnorm,
                                                   ushortT* __restrict__ apad, int b0)
{
    int bl = blockIdx.z, bg = b0 + bl;
    int hw0 = blockIdx.x * 128;
    int o0 = blockIdx.y * 128;
    int tid = threadIdx.x, wave = tid >> 6, lane = tid & 63;
    int wm = wave >> 1, wn = wave & 1;
    int lr = lane & 15, kb = lane >> 4;

    __shared__ __align__(16) char smem[33280];   // 2x16KB stage bufs; T overlays

    const uint4* MbC = (const uint4*)Mb16 + (size_t)bg * 32 * 256;
    const uint4* fpC = (const uint4*)fpack + (size_t)bg * 32 * HWSZ;

    f32x4 acc[4][4] = {};

    auto STAGE = [&](int buf, int s) {
        int cb0 = s * 4;
        uint4* A = (uint4*)smem + (size_t)buf * 1024;
        uint4* B = A + 512;
#pragma unroll
        for (int i = 0; i < 2; ++i) {
            int e = tid + i * 256;
            int kk = e >> 7, j = e & 127;
            gload16(MbC + (size_t)(cb0 + kk) * 256 + o0 + j, A + e);
            gload16(fpC + (size_t)(cb0 + kk) * HWSZ + hw0 + j, B + e);
        }
    };

    STAGE(0, 0);
    for (int s = 0; s < 8; ++s) {
        int buf = s & 1;
        __syncthreads();                     // drains prev stage (vmcnt0+barrier)
        if (s < 7) STAGE(buf ^ 1, s + 1);
        const bf16x8* AsV = (const bf16x8*)(smem + (size_t)buf * 16384);
        const bf16x8* BsV = AsV + 512;
        bf16x8 af[4], bfv[4];
#pragma unroll
        for (int mf = 0; mf < 4; ++mf) af[mf] = AsV[kb * 128 + wm * 64 + mf * 16 + lr];
#pragma unroll
        for (int nf = 0; nf < 4; ++nf) bfv[nf] = BsV[kb * 128 + wn * 64 + nf * 16 + lr];
#pragma unroll
        for (int mf = 0; mf < 4; ++mf)
#pragma unroll
            for (int nf = 0; nf < 4; ++nf)
                acc[mf][nf] = __builtin_amdgcn_mfma_f32_16x16x32_bf16(af[mf], bfv[nf], acc[mf][nf], 0, 0, 0);
    }
    __syncthreads();

    float rn[4];
#pragma unroll
    for (int nf = 0; nf < 4; ++nf)
        rn[nf] = rnorm[(size_t)bg * HWSZ + hw0 + wn * 64 + nf * 16 + lr];

    // transpose through LDS: T[hw_local][o_local], stride 130
    ushortT* T = (ushortT*)smem;
#pragma unroll
    for (int mf = 0; mf < 4; ++mf)
#pragma unroll
        for (int nf = 0; nf < 4; ++nf)
#pragma unroll
            for (int r = 0; r < 4; ++r)
                T[(wn * 64 + nf * 16 + lr) * 130 + wm * 64 + mf * 16 + kb * 4 + r] =
                    f2bfu(acc[mf][nf][r] * rn[nf]);
    __syncthreads();

    uint4* apC = (uint4*)apad + (size_t)bl * APAD_CHUNKS;
    int ob0 = blockIdx.y * 16;
#pragma unroll
    for (int i = 0; i < 8; ++i) {
        int e = tid + i * 256;
        int hw_l = e >> 4, ob = e & 15;
        uint4 v = *(uint4*)&T[hw_l * 130 + ob * 8];
        int hw = hw0 + hw_l;
        int h = hw / 96, w = hw - h * 96;
        apC[(size_t)((h + 1) * 32 + ob0 + ob) * 98 + (w + 1)] = v;
    }
}

// ---------------------------------------------------------------------------
// instance-norm stats from apad (bf16): per (bl, ob) block -> 8 o's
__global__ void instats2_k(const ushortT* __restrict__ apad, float* __restrict__ mu,
                           float* __restrict__ istd)
{
    int ob = blockIdx.x, bl = blockIdx.y;
    const uint4* apC = (const uint4*)apad + (size_t)bl * APAD_CHUNKS;
    float s[8] = {}, s2[8] = {};
    for (int e = threadIdx.x; e < HWSZ; e += 256) {
        int row = e / 96;
        int w = e - row * 96;
        uint4 v = apC[(size_t)((row + 1) * 32 + ob) * 98 + w + 1];
        const ushortT* u = (const ushortT*)&v;
#pragma unroll
        for (int k = 0; k < 8; ++k) {
            float f = bfu2f(u[k]);
            s[k] += f; s2[k] += f * f;
        }
    }
#pragma unroll
    for (int off = 32; off > 0; off >>= 1) {
#pragma unroll
        for (int k = 0; k < 8; ++k) {
            s[k]  += __shfl_down(s[k],  off, 64);
            s2[k] += __shfl_down(s2[k], off, 64);
        }
    }
    __shared__ float sh[4][16];
    int wid = threadIdx.x >> 6;
    if ((threadIdx.x & 63) == 0) {
#pragma unroll
        for (int k = 0; k < 8; ++k) { sh[wid][k] = s[k]; sh[wid][8 + k] = s2[k]; }
    }
    __syncthreads();
    if (threadIdx.x < 8) {
        int k = threadIdx.x;
        float S  = sh[0][k] + sh[1][k] + sh[2][k] + sh[3][k];
        float S2 = sh[0][8 + k] + sh[1][8 + k] + sh[2][8 + k] + sh[3][8 + k];
        float m   = S * (1.0f / HWSZ);
        float var = S2 * (1.0f / HWSZ) - m * m;
        if (var < 0.f) var = 0.f;
        mu[bl * 256 + ob * 8 + k]   = m;
        istd[bl * 256 + ob * 8 + k] = rsqrtf(var + 1e-5f);
    }
}

// ---------------------------------------------------------------------------
// in-place normalize+relu on apad interior. grid (96, nb)
__global__ void nr_k(ushortT* __restrict__ apad, const float* __restrict__ mu,
                     const float* __restrict__ istd)
{
    int row = blockIdx.x + 1, bl = blockIdx.y;
    __shared__ float smu[256], sis[256];
    smu[threadIdx.x] = mu[bl * 256 + threadIdx.x];
    sis[threadIdx.x] = istd[bl * 256 + threadIdx.x];
    __syncthreads();
    uint4* apC = (uint4*)apad + (size_t)bl * APAD_CHUNKS + (size_t)row * 32 * 98;
    for (int e = threadIdx.x; e < 3072; e += 256) {
        int ob = e / 96;
        int w = e - ob * 96 + 1;
        uint4 v = apC[(size_t)ob * 98 + w];
        ushortT* u = (ushortT*)&v;
#pragma unroll
        for (int k = 0; k < 8; ++k) {
            float f = (bfu2f(u[k]) - smu[ob * 8 + k]) * sis[ob * 8 + k];
            u[k] = f2bfu(f > 0.f ? f : 0.f);
        }
        apC[(size_t)ob * 98 + w] = v;
    }
}

// ---------------------------------------------------------------------------
// 3x3 conv implicit-GEMM MFMA v4: 4 output rows per block. (r6-exact, best)
// Block: 64 o x 4 rows x 96 w; wave = its output row; acc[4][6].
// c-loop: 8 iters x 32 channels. Per iter: stage A for ALL 9 taps (2304
// chunks) + B as 6 contiguous input rows (2352 chunks) -- kh resolved by
// LDS row indexing, no kh re-staging. LDS 77824 B single-buffered
// (2 blocks/CU -- the 2 independent blocks provide stage/compute overlap).
// B padded to 2560 chunks: stage loop writes e in [2352,2560) with clamped
// source -- padding is load-bearing (LDS dest of global_load_lds is
// base+lane*16 and cannot be clamped per-lane).
// grid (24, 4, nb) = 1536 blocks = 3 exact rounds at 2 blocks/CU.
__global__ __launch_bounds__(256, 2) void conv3m4_k(const ushortT* __restrict__ apad,
                                                    const ushortT* __restrict__ W2r2,
                                                    const float* __restrict__ b2,
                                                    float* __restrict__ out)
{
    int h0 = blockIdx.x * 4;
    int o0 = blockIdx.y * 64;
    int bl = blockIdx.z;
    int tid = threadIdx.x;
    int wave = tid >> 6, lane = tid & 63;   // wave = output row within tile
    int lr = lane & 15, kb = lane >> 4;

    __shared__ __align__(16) uint4 AsC[2304];   // [s9][kk4][o64]
    __shared__ __align__(16) uint4 BsC[2560];   // [row6][kk4][w98], 2352 used

    const uint4* apadC = (const uint4*)apad + (size_t)bl * APAD_CHUNKS;
    const uint4* w2C   = (const uint4*)W2r2;
    const bf16x8* AsV = (const bf16x8*)AsC;
    const bf16x8* BsV = (const bf16x8*)BsC;

    f32x4 acc[4][6] = {};

    for (int ci = 0; ci < 8; ++ci) {
        int cb0 = ci * 4;
        __syncthreads();                    // all waves done reading prev iter
#pragma unroll
        for (int i = 0; i < 9; ++i) {       // A: 2304 chunks exact
            int e = tid + i * 256;
            int o = e & 63, kk = (e >> 6) & 3, s = e >> 8;
            gload16(w2C + (size_t)(s * 32 + cb0 + kk) * 256 + o0 + o, &AsC[e]);
        }
#pragma unroll
        for (int i = 0; i < 10; ++i) {      // B: 2352 real + 208 pad writes
            int e = tid + i * 256;
            int se = e < 2352 ? e : e - 256;  // clamp SOURCE only; dest padded
            int w = se % 98, r = se / 98;
            int kk = r & 3, row = r >> 2;     // apad row h0+row, row<6
            gload16(apadC + (size_t)((h0 + row) * 32 + cb0 + kk) * 98 + w, &BsC[e]);
        }
        __syncthreads();                    // vmcnt(0) drain: stage ready
#pragma unroll
        for (int kh = 0; kh < 3; ++kh) {
#pragma unroll
            for (int kw = 0; kw < 3; ++kw) {
                int s = kh * 3 + kw;
                bf16x8 af[4];
#pragma unroll
                for (int mf = 0; mf < 4; ++mf)
                    af[mf] = AsV[(s * 4 + kb) * 64 + mf * 16 + lr];
#pragma unroll
                for (int nf = 0; nf < 6; ++nf) {
                    bf16x8 bfr = BsV[((wave + kh) * 4 + kb) * 98 + nf * 16 + lr + kw];
#pragma unroll
                    for (int mf = 0; mf < 4; ++mf)
                        acc[mf][nf] = __builtin_amdgcn_mfma_f32_16x16x32_bf16(af[mf], bfr, acc[mf][nf], 0, 0, 0);
                }
            }
        }
    }

    // epilogue: wave's output row h0+wave; C row(o)=mf*16+kb*4+r, col(w)=nf*16+lr
    int h = h0 + wave;
    float* obase = out + (size_t)bl * FCH * HWSZ + (size_t)h * WW;
#pragma unroll
    for (int mf = 0; mf < 4; ++mf) {
#pragma unroll
        for (int r = 0; r < 4; ++r) {
            int o = o0 + mf * 16 + kb * 4 + r;
            float bias = b2[o];
            float* orow = obase + (size_t)o * HWSZ;
#pragma unroll
            for (int nf = 0; nf < 6; ++nf)
                orow[nf * 16 + lr] = acc[mf][nf][r] + bias;
        }
    }
}

// ---------------------------------------------------------------------------
extern "C" void kernel_launch(void* const* d_in, const int* in_sizes, int n_in,
                              void* d_out, int out_size, void* d_ws, size_t ws_size,
                              hipStream_t stream)
{
    const float* Fir  = (const float*)d_in[0];
    const float* Fvis = (const float*)d_in[1];
    const float* W1   = (const float*)d_in[2];
    // d_in[3] = b1: canceled exactly by InstanceNorm -> unused
    const float* W2   = (const float*)d_in[4];
    const float* b2   = (const float*)d_in[5];
    float* out = (float*)d_out;

    char* w = (char*)d_ws;
    const size_t poolB = (size_t)BATCH * CH * PP * 4;        // 4 MB
    const size_t MbB   = (size_t)BATCH * 32 * 256 * 8 * 2;   // 2 MB
    const size_t rnB   = (size_t)BATCH * HWSZ * 4;           // 0.56 MB
    const size_t stB   = (size_t)BATCH * FCH * 4;            // 16 KB
    const size_t w2rB  = (size_t)9 * 32 * 256 * 8 * 2;       // 1.125 MB
    const size_t fpB   = (size_t)BATCH * 32 * HWSZ * 8 * 2;  // 75.5 MB

    size_t off = 0;
    float*   pooled = (float*)(w + off);   off += poolB;
    ushortT* Mb16   = (ushortT*)(w + off); off += MbB;
    float*   rnorm  = (float*)(w + off);   off += rnB;
    float*   mu     = (float*)(w + off);   off += stB;
    float*   istd   = (float*)(w + off);   off += stB;
    ushortT* W2r2   = (ushortT*)(w + off); off += w2rB;
    ushortT* fpack  = (ushortT*)(w + off); off += fpB;
    const size_t fixed = off;

    const size_t apadB = (size_t)APAD_ELEMS * 2;             // 4.92 MB / batch
    size_t avail = ws_size > fixed ? ws_size - fixed : 0;
    int NB = (int)(avail / apadB);
    if (NB > BATCH) NB = BATCH;
    if (NB < 1) NB = 1;
    ushortT* apad = (ushortT*)(w + fixed);

    repack_w2_k<<<2304, 256, 0, stream>>>(W2, W2r2);
    zborder_k<<<NB, 256, 0, stream>>>((uint4*)apad);

    for (int f = 0; f < 2; ++f) {
        const float* feat = (f == 0) ? Fir : Fvis;   // IR first in output
        float* o_ = out + (size_t)f * BATCH * FCH * HWSZ;

        fpack_k<<<dim3(36, BATCH), 256, 0, stream>>>(feat, fpack, rnorm);
        pool16b_k<<<dim3(32, BATCH), 256, 0, stream>>>(fpack, pooled);
        gemmM_k<<<dim3(16, 16, BATCH), dim3(16, 16), 0, stream>>>(W1, pooled, Mb16);

        for (int b0 = 0; b0 < BATCH; b0 += NB) {
            int nb = BATCH - b0 < NB ? BATCH - b0 : NB;
            gemmYm_k<<<dim3(72, 2, nb), 256, 0, stream>>>(Mb16, fpack, rnorm, apad, b0);
            instats2_k<<<dim3(32, nb), 256, 0, stream>>>(apad, mu, istd);
            nr_k<<<dim3(96, nb), 256, 0, stream>>>(apad, mu, istd);
            conv3m4_k<<<dim3(24, 4, nb), 256, 0, stream>>>(apad, W2r2, b2,
                                                           o_ + (size_t)b0 * FCH * HWSZ);
        }
    }
}